// Round 5
// baseline (692.939 us; speedup 1.0000x reference)
//
#include <hip/hip_runtime.h>
#include <hip/hip_fp16.h>
#include <hip/hip_bf16.h>
#include <stdint.h>

// ---------------------------------------------------------------------------
// ResidualVQ: x (64,512,256) f32, codebooks (6,1024,512) f32
// outputs: quantized_out (64,512,256), indices (64,256,6) as f32,
//          mean_loss, mean_perplexity   -> d_out flat f32, 8486914 elems
//
// R9 -> R10: SECOND INSTRUMENTATION ROUND. R9 established t_gemm ~= 22us
// (6x gemm = 132 of 471us). Remaining 339us split across prep/6xrefine/
// final/overhead is unattributed (floors say ~110us -> ~225us fog).
// This round: shadow-refine probe. refine_kernel signature split into
// r_in/r_out (real launches pass same ptr -> identical behavior); a
// shadow refine per stage reads REAL r/cand/cbq (identical trip counts,
// identical codegen) and writes to scratch at ws+64MiB (ws = 256MiB per
// the 262144KB harness fills; guarded by ws_size check).
//   T'' - 471 = 6 * t_refine.  Pre-committed readout:
//   delta 150-220 -> refine-dominant -> rework refine next
//   delta  80-150 -> overhead-dominant -> coop mega-fusion next
// GEMM/prep/final byte-identical to R8.
// ---------------------------------------------------------------------------

#define NTROWS 16384
#define DDIM   512
#define CCODES 1024
#define QSTAGE 6

// ws layout (bytes)
#define OFF_R      ((size_t)0)           // fp32 residual  NT*D*4   = 33554432
#define OFF_RBF    ((size_t)33554432)    // bf16 residual  NT*D*2   = 16777216
#define OFF_CBBF   ((size_t)50331648)    // bf16 codebooks 6*1024*512*2 = 6291456
#define OFF_CAND   ((size_t)56623104)    // u32 cand       NT*32*4   = 2097152
#define OFF_CBSQ   ((size_t)58720256)    // f32 |c|^2, 6*1024*4
#define OFF_HIST   ((size_t)58744832)    // u32 hist, 6*1024*4
#define OFF_LOSS   ((size_t)58769408)    // f32 loss bins, 6*256*4
#define WS_END     ((size_t)58775552)

// shadow region (instrumentation only; ws is 256 MiB per harness fill size)
#define OFF_RSH    ((size_t)0x4000000)   //  64 MiB: r_shadow 33.5 MB
#define OFF_RBFSH  ((size_t)0x6400000)   // 100 MiB: rbf_shadow 16.8 MB
#define OFF_HISTSH ((size_t)0x7800000)   // 120 MiB: hist shadow 24 KB
#define OFF_LOSSSH ((size_t)0x7810000)   // loss shadow 6 KB
#define OFF_IDXSH  ((size_t)0x7900000)   // idx shadow 393 KB
#define SH_END     ((size_t)(OFF_IDXSH + 0x100000))

#define OUT_IDX_OFF  ((size_t)8388608)
#define OUT_SCAL_OFF ((size_t)8486912)

typedef __attribute__((ext_vector_type(8))) short short8;
typedef __attribute__((ext_vector_type(8))) unsigned short ushort8v;
typedef __attribute__((ext_vector_type(4))) float f32x4;

__device__ __forceinline__ unsigned short f2bf(float f) {
    uint32_t u = __float_as_uint(f);
    uint32_t r = (u + 0x7fffu + ((u >> 16) & 1u)) >> 16;   // RNE
    return (unsigned short)r;
}
__device__ __forceinline__ uint32_t fkey(float f) {        // order-preserving f32->u32
    uint32_t u = __float_as_uint(f);
    return u ^ ((uint32_t)((int32_t)u >> 31) | 0x80000000u);
}
__device__ __forceinline__ float funkey(uint32_t k) {
    uint32_t u = (k & 0x80000000u) ? (k ^ 0x80000000u) : ~k;
    return __uint_as_float(u);
}
__device__ __forceinline__ uint32_t umin32(uint32_t a, uint32_t b) { return a < b ? a : b; }
__device__ __forceinline__ uint32_t umax32(uint32_t a, uint32_t b) { return a > b ? a : b; }
__device__ __forceinline__ float wave_sum(float v) {
    for (int m = 32; m; m >>= 1) v += __shfl_xor(v, m, 64);
    return v;
}
__device__ __forceinline__ uint32_t wave_min_u32(uint32_t v) {
    for (int m = 32; m; m >>= 1) v = umin32(v, (uint32_t)__shfl_xor((int)v, m, 64));
    return v;
}
__device__ __forceinline__ void async_load16(const void* g, void* l) {
    __builtin_amdgcn_global_load_lds(
        (__attribute__((address_space(1))) void*)(void*)g,
        (__attribute__((address_space(3))) void*)l, 16, 0, 0);
}

// --------------------------------------------------------------------------
// prep: blocks [0,1536): bf16 codebooks + |c|^2 (+ zero hist/loss in blk 0)
//       blocks [1536,9728): transpose x (N,D,T) -> r (NT,D) fp32+bf16
// grid 9728 x 256
// --------------------------------------------------------------------------
__global__ __launch_bounds__(256) void prep_kernel(
    const float* __restrict__ x, const float* __restrict__ cb,
    float* __restrict__ r, unsigned short* __restrict__ rbf,
    unsigned short* __restrict__ cbbf, float* __restrict__ cbsq,
    unsigned int* __restrict__ hist, float* __restrict__ loss_bins)
{
    __shared__ float tile[32][33];
    if (blockIdx.x < 1536) {
        const int wave = threadIdx.x >> 6, lane = threadIdx.x & 63;
        const int row = blockIdx.x * 4 + wave;            // 0..6143
        const float* p = cb + (size_t)row * DDIM;
        unsigned short* pb = cbbf + (size_t)row * DDIM;
        float s = 0.f;
#pragma unroll
        for (int t = 0; t < 8; ++t) {
            float v = p[lane + 64 * t];
            pb[lane + 64 * t] = f2bf(v);
            s += v * v;
        }
        s = wave_sum(s);
        if (lane == 0) cbsq[row] = s;
        if (blockIdx.x == 0) {
            for (int i = threadIdx.x; i < QSTAGE * CCODES; i += 256) hist[i] = 0u;
            for (int i = threadIdx.x; i < QSTAGE * 256; i += 256) loss_bins[i] = 0.f;
        }
    } else {
        const int bidx = blockIdx.x - 1536;               // 0..8191
        const int d0 = (bidx & 15) * 32;
        const int t0 = ((bidx >> 4) & 7) * 32;
        const int n  = bidx >> 7;
        const int tx = threadIdx.x & 31, ty = threadIdx.x >> 5;
        const float* xp = x + (size_t)n * (DDIM * 256);
#pragma unroll
        for (int s = 0; s < 4; ++s) {
            int dd = ty + s * 8;
            tile[dd][tx] = xp[(size_t)(d0 + dd) * 256 + t0 + tx];
        }
        __syncthreads();
#pragma unroll
        for (int s = 0; s < 4; ++s) {
            int tt = ty + s * 8;
            float v = tile[tx][tt];
            size_t off = (size_t)(n * 256 + t0 + tt) * DDIM + d0 + tx;
            r[off] = v;
            rbf[off] = f2bf(v);
        }
    }
}

// --------------------------------------------------------------------------
// GEMM: dist'[row][col] = cbsq[col] - 2 * dot(r_row, c_col), bf16 MFMA.
// 256x256 block tile, BK=32, 4-deep LDS ring, counted vmcnt, 2-phase
// 16-MFMA grain. grid (64, 4) x 512 : tm = blockIdx.x, tn = blockIdx.y
// --------------------------------------------------------------------------
#define GBK 32
__global__ __launch_bounds__(512, 2) void gemm_dist_kernel(
    const unsigned short* __restrict__ Abf,   // NT x 512 bf16
    const unsigned short* __restrict__ Bbf,   // 1024 x 512 bf16 (stage slice)
    const float* __restrict__ cbsq,           // 1024 (stage slice)
    uint32_t* __restrict__ cand)              // NT x 16 x {k1,k2}
{
    __shared__ __align__(16) unsigned short lA[4][256][GBK];   // 64 KiB
    __shared__ __align__(16) unsigned short lB[4][256][GBK];   // 64 KiB
    const int tid = threadIdx.x;
    const int wave = tid >> 6, lane = tid & 63;
    const int quad = lane >> 4, l15 = lane & 15;
    const int tm = blockIdx.x, tn = blockIdx.y;
    const int wm = wave >> 2, wn = wave & 3;

    f32x4 acc[8][4];
#pragma unroll
    for (int i = 0; i < 8; ++i)
#pragma unroll
        for (int j = 0; j < 4; ++j) acc[i][j] = (f32x4){0.f, 0.f, 0.f, 0.f};

    const int srow = wave * 32 + (lane >> 2);
    const int gch  = (lane & 3) ^ ((lane >> 3) & 3);
    const unsigned short* gA0 = Abf + ((size_t)tm * 256 + srow) * DDIM + gch * 8;
    const unsigned short* gA1 = gA0 + 16 * DDIM;
    const unsigned short* gB0 = Bbf + ((size_t)tn * 256 + srow) * DDIM + gch * 8;
    const unsigned short* gB1 = gB0 + 16 * DDIM;
    const int dro0 = wave * 32, dro1 = wave * 32 + 16;

    // prologue: stage K-tiles 0,1,2 (12 issues/wave in flight)
#pragma unroll
    for (int st = 0; st < 3; ++st) {
        const size_t ko = (size_t)st * GBK;
        async_load16(gA0 + ko, &lA[st][dro0][0] + lane * 8);
        async_load16(gA1 + ko, &lA[st][dro1][0] + lane * 8);
        async_load16(gB0 + ko, &lB[st][dro0][0] + lane * 8);
        async_load16(gB1 + ko, &lB[st][dro1][0] + lane * 8);
    }
    asm volatile("s_waitcnt vmcnt(8)" ::: "memory");   // tile 0 landed
    __builtin_amdgcn_s_barrier();

    const int cq = (quad ^ ((l15 >> 1) & 3)) * 8;   // swizzled chunk addr

#pragma unroll
    for (int kt = 0; kt < 16; ++kt) {
        const int buf = kt & 3;
        const int sb  = (kt + 3) & 3;              // ring slot for tile kt+3
        const size_t ko = (size_t)(kt + 3) * GBK;

        // ================= phase 0: quadrant mh=0 =================
        short8 afA[4], bfr[4];
#pragma unroll
        for (int i = 0; i < 4; ++i)
            afA[i] = *(const short8*)&lA[buf][wm * 128 + i * 16 + l15][cq];
#pragma unroll
        for (int j = 0; j < 4; ++j)
            bfr[j] = *(const short8*)&lB[buf][wn * 64 + j * 16 + l15][cq];
        if (kt <= 12) {   // stage A-half of tile kt+3 (slot last read at kt-1)
            async_load16(gA0 + ko, &lA[sb][dro0][0] + lane * 8);
            async_load16(gA1 + ko, &lA[sb][dro1][0] + lane * 8);
        }
        __builtin_amdgcn_s_barrier();
        asm volatile("s_waitcnt lgkmcnt(0)" ::: "memory");
        __builtin_amdgcn_sched_barrier(0);         // rule #18
        __builtin_amdgcn_s_setprio(1);
#pragma unroll
        for (int i = 0; i < 4; ++i)
#pragma unroll
            for (int j = 0; j < 4; ++j)
                acc[i][j] = __builtin_amdgcn_mfma_f32_16x16x32_bf16(
                    afA[i], bfr[j], acc[i][j], 0, 0, 0);
        __builtin_amdgcn_s_setprio(0);
        __builtin_amdgcn_s_barrier();

        // ================= phase 1: quadrant mh=1 =================
        short8 afB[4];
#pragma unroll
        for (int i = 0; i < 4; ++i)
            afB[i] = *(const short8*)&lA[buf][wm * 128 + (i + 4) * 16 + l15][cq];
        if (kt <= 12) {   // stage B-half of tile kt+3
            async_load16(gB0 + ko, &lB[sb][dro0][0] + lane * 8);
            async_load16(gB1 + ko, &lB[sb][dro1][0] + lane * 8);
        }
        __builtin_amdgcn_s_barrier();
        asm volatile("s_waitcnt lgkmcnt(0)" ::: "memory");
        __builtin_amdgcn_sched_barrier(0);         // rule #18
        __builtin_amdgcn_s_setprio(1);
#pragma unroll
        for (int i = 0; i < 4; ++i)
#pragma unroll
            for (int j = 0; j < 4; ++j)
                acc[i + 4][j] = __builtin_amdgcn_mfma_f32_16x16x32_bf16(
                    afB[i], bfr[j], acc[i + 4][j], 0, 0, 0);
        __builtin_amdgcn_s_setprio(0);

        // tile boundary: counted — tiles kt+2,kt+3 (8 issues) stay in flight.
        if (kt <= 12)      asm volatile("s_waitcnt vmcnt(8)" ::: "memory");
        else if (kt == 13) asm volatile("s_waitcnt vmcnt(4)" ::: "memory");
        else if (kt == 14) asm volatile("s_waitcnt vmcnt(0)" ::: "memory");
        if (kt < 15) __builtin_amdgcn_s_barrier();
    }

    // epilogue: C/D layout col=lane&15, row=quad*4+reg (m89-verified).
    const int rowq = tm * 256 + wm * 128 + quad * 4;
    const int colb = tn * 256 + wn * 64 + l15;
    const int g    = tn * 4 + wn;
    float cbs[4];
#pragma unroll
    for (int j = 0; j < 4; ++j) cbs[j] = cbsq[colb + j * 16];
#pragma unroll
    for (int i = 0; i < 8; ++i) {
#pragma unroll
        for (int reg = 0; reg < 4; ++reg) {
            const int row = rowq + i * 16 + reg;
            uint32_t k[4];
#pragma unroll
            for (int j = 0; j < 4; ++j) {
                float dv = cbs[j] - 2.0f * acc[i][j][reg];
                k[j] = (fkey(dv) & ~1023u) | (uint32_t)(colb + j * 16);
            }
            // top-2 of 4 (tournament)
            uint32_t m01 = umin32(k[0], k[1]), M01 = umax32(k[0], k[1]);
            uint32_t m23 = umin32(k[2], k[3]), M23 = umax32(k[2], k[3]);
            uint32_t k1 = umin32(m01, m23);
            uint32_t k2 = umin32(umax32(m01, m23), umin32(M01, M23));
            // merge across the 16 lanes of this quad (xor stays in-quad)
#pragma unroll
            for (int m = 1; m < 16; m <<= 1) {
                uint32_t o1 = (uint32_t)__shfl_xor((int)k1, m, 64);
                uint32_t o2 = (uint32_t)__shfl_xor((int)k2, m, 64);
                uint32_t n1 = umin32(k1, o1);
                uint32_t n2 = umin32(umax32(k1, o1), umin32(k2, o2));
                k1 = n1; k2 = n2;
            }
            if (l15 == 0)
                *(uint2*)&cand[((size_t)row * 16 + g) * 2] = make_uint2(k1, k2);
        }
    }
}

// --------------------------------------------------------------------------
// refine+update: read 32 packed candidates/row, exact fp32 recompute for all
// entries within MARGIN of approx min; r_out = r_in - cb[best]; fp32+bf16;
// loss += best (256-bin atomics); hist; index out.
// r_in/r_out split: real launches pass the SAME pointer (behavior identical
// to R8); shadow launches read real r, write scratch (instrumentation).
// grid 4096 x 256 (wave per row, lane owns 8 contiguous d)
// --------------------------------------------------------------------------
#define MARGIN 8.0f
__global__ __launch_bounds__(256) void refine_kernel(
    const float* __restrict__ r_in, float* __restrict__ r_out,
    unsigned short* __restrict__ rbf,
    const float* __restrict__ cbq, const float* __restrict__ cbsqq,
    const uint32_t* __restrict__ cand,
    float* __restrict__ out_idx, unsigned int* __restrict__ histq,
    float* __restrict__ loss_bins, int q, int write_bf)
{
    const int wave = threadIdx.x >> 6, lane = threadIdx.x & 63;
    const int nt = blockIdx.x * 4 + wave;

    const float4* r4 = (const float4*)(r_in + (size_t)nt * DDIM);
    float4 ra = r4[lane * 2], rb = r4[lane * 2 + 1];
    float s = ra.x * ra.x + ra.y * ra.y + ra.z * ra.z + ra.w * ra.w
            + rb.x * rb.x + rb.y * rb.y + rb.z * rb.z + rb.w * rb.w;
    const float sumx = wave_sum(s);

    uint32_t key = 0xFFFFFFFFu;
    if (lane < 32) key = cand[(size_t)nt * 32 + lane];
    const uint32_t kmin = wave_min_u32(key);
    const float thr = funkey(kmin & ~1023u) + MARGIN;

    unsigned long long mask = __ballot(lane < 32 && funkey(key & ~1023u) <= thr);

    float best = 1e30f;
    int bestc = CCODES;
    while (mask) {
        const int src = __ffsll(mask) - 1;
        mask &= mask - 1;
        const int cc = __shfl((int)(key & 1023u), src, 64);
        const float4* crow = (const float4*)(cbq + (size_t)cc * DDIM);
        float4 ca = crow[lane * 2], cb2 = crow[lane * 2 + 1];
        float dot = ra.x * ca.x + ra.y * ca.y + ra.z * ca.z + ra.w * ca.w
                  + rb.x * cb2.x + rb.y * cb2.y + rb.z * cb2.z + rb.w * cb2.w;
        dot = wave_sum(dot);
        const float de = (sumx - 2.0f * dot) + cbsqq[cc];
        if (de < best || (de == best && cc < bestc)) { best = de; bestc = cc; }
    }

    // merged residual update: bestc/best are wave-uniform
    const float4* cbest = (const float4*)(cbq + (size_t)bestc * DDIM);
    float4 ba = cbest[lane * 2], bb = cbest[lane * 2 + 1];
    float4 na = make_float4(ra.x - ba.x, ra.y - ba.y, ra.z - ba.z, ra.w - ba.w);
    float4 nb = make_float4(rb.x - bb.x, rb.y - bb.y, rb.z - bb.z, rb.w - bb.w);
    float4* rw = (float4*)(r_out + (size_t)nt * DDIM);
    rw[lane * 2] = na; rw[lane * 2 + 1] = nb;
    if (write_bf) {
        ushort8v pk;
        pk[0] = f2bf(na.x); pk[1] = f2bf(na.y); pk[2] = f2bf(na.z); pk[3] = f2bf(na.w);
        pk[4] = f2bf(nb.x); pk[5] = f2bf(nb.y); pk[6] = f2bf(nb.z); pk[7] = f2bf(nb.w);
        *(ushort8v*)(rbf + (size_t)nt * DDIM + lane * 8) = pk;
    }

    if (lane == 0) {
        out_idx[(size_t)nt * QSTAGE + q] = (float)bestc;
        atomicAdd(&histq[bestc], 1u);
        atomicAdd(&loss_bins[q * 256 + (blockIdx.x & 255)], best);
    }
}

// --------------------------------------------------------------------------
// final: blocks [0,8192): out = x - r_final transposed back to (N,D,T);
//        block 8192: mean commit loss + mean perplexity
// grid 8193 x 256
// --------------------------------------------------------------------------
__global__ __launch_bounds__(256) void final_kernel(
    const float* __restrict__ x, const float* __restrict__ r,
    float* __restrict__ out,
    const unsigned int* __restrict__ hist, const float* __restrict__ loss_bins,
    float* __restrict__ out2)
{
    __shared__ float tile[32][33];    // [t'][d']
    __shared__ float red[4];
    __shared__ float perp_acc;
    const int tid = threadIdx.x, wave = tid >> 6, lane = tid & 63;

    if (blockIdx.x < 8192) {
        const int bidx = blockIdx.x;
        const int d0 = (bidx & 15) * 32;
        const int t0 = ((bidx >> 4) & 7) * 32;
        const int n  = bidx >> 7;
        const int tx = tid & 31, ty = tid >> 5;
#pragma unroll
        for (int s = 0; s < 4; ++s) {
            int tt = ty + s * 8;
            tile[tt][tx] = r[(size_t)(n * 256 + t0 + tt) * DDIM + d0 + tx];
        }
        __syncthreads();
        const float* xp = x + (size_t)n * (DDIM * 256);
        float* op = out + (size_t)n * (DDIM * 256);
#pragma unroll
        for (int s = 0; s < 4; ++s) {
            int dd = ty + s * 8;
            size_t off = (size_t)(d0 + dd) * 256 + t0 + tx;
            op[off] = xp[off] - tile[tx][dd];
        }
        return;
    }

    // scalars block
    if (tid == 0) perp_acc = 0.f;
    __syncthreads();
    for (int q = 0; q < QSTAGE; ++q) {
        float s = 0.f;
        for (int c = tid; c < CCODES; c += 256) {
            float p = (float)hist[q * CCODES + c] * (1.0f / (float)NTROWS);
            s += p * logf(p + 1e-10f);
        }
        s = wave_sum(s);
        if (lane == 0) red[wave] = s;
        __syncthreads();
        if (tid == 0) {
            float tot = red[0] + red[1] + red[2] + red[3];
            perp_acc += expf(-tot);
        }
        __syncthreads();
    }
    float ls = 0.f;
    for (int i = tid; i < QSTAGE * 256; i += 256) ls += loss_bins[i];
    ls = wave_sum(ls);
    if (lane == 0) red[wave] = ls;
    __syncthreads();
    if (tid == 0) {
        float lsum = red[0] + red[1] + red[2] + red[3];
        out2[0] = (lsum / (float)QSTAGE) / ((float)NTROWS * (float)DDIM);
        out2[1] = perp_acc / (float)QSTAGE;
    }
}

// --------------------------------------------------------------------------
extern "C" void kernel_launch(void* const* d_in, const int* in_sizes, int n_in,
                              void* d_out, int out_size, void* d_ws, size_t ws_size,
                              hipStream_t stream)
{
    const float* x  = (const float*)d_in[0];
    const float* cb = (const float*)d_in[1];
    float* out = (float*)d_out;
    char* ws = (char*)d_ws;

    float*          r      = (float*)(ws + OFF_R);
    unsigned short* rbf    = (unsigned short*)(ws + OFF_RBF);
    unsigned short* cbbf   = (unsigned short*)(ws + OFF_CBBF);
    uint32_t*       cand   = (uint32_t*)(ws + OFF_CAND);
    float*          cbsq   = (float*)(ws + OFF_CBSQ);
    unsigned int*   hist   = (unsigned int*)(ws + OFF_HIST);
    float*          lbins  = (float*)(ws + OFF_LOSS);

    // shadow scratch (instrumentation)
    const bool do_shadow = (ws_size >= SH_END);
    float*          r_sh    = (float*)(ws + OFF_RSH);
    unsigned short* rbf_sh  = (unsigned short*)(ws + OFF_RBFSH);
    unsigned int*   hist_sh = (unsigned int*)(ws + OFF_HISTSH);
    float*          lbin_sh = (float*)(ws + OFF_LOSSSH);
    float*          idx_sh  = (float*)(ws + OFF_IDXSH);

    prep_kernel<<<9728, 256, 0, stream>>>(x, cb, r, rbf, cbbf, cbsq, hist, lbins);

    for (int q = 0; q < QSTAGE; ++q) {
        const size_t cboff = (size_t)q * CCODES * DDIM;
        gemm_dist_kernel<<<dim3(64, 4), 512, 0, stream>>>(
            rbf, cbbf + cboff, cbsq + q * CCODES, cand);
        // INSTRUMENTATION: shadow refine — identical reads (real r/cand/cbq,
        // same mask & trip counts), writes to scratch. T'' - T_R8 = 6*t_refine.
        if (do_shadow)
            refine_kernel<<<4096, 256, 0, stream>>>(
                r, r_sh, rbf_sh, cb + cboff, cbsq + q * CCODES, cand,
                idx_sh, hist_sh, lbin_sh, q, (q < QSTAGE - 1) ? 1 : 0);
        refine_kernel<<<4096, 256, 0, stream>>>(
            r, r, rbf, cb + cboff, cbsq + q * CCODES, cand,
            out + OUT_IDX_OFF, hist + q * CCODES, lbins,
            q, (q < QSTAGE - 1) ? 1 : 0);
    }

    final_kernel<<<8193, 256, 0, stream>>>(x, r, out, hist, lbins,
                                           out + OUT_SCAL_OFF);
}

// Round 6
// 453.881 us; speedup vs baseline: 1.5267x; 1.5267x over previous
//
#include <hip/hip_runtime.h>
#include <hip/hip_fp16.h>
#include <hip/hip_bf16.h>
#include <stdint.h>

// ---------------------------------------------------------------------------
// ResidualVQ: x (64,512,256) f32, codebooks (6,1024,512) f32
// outputs: quantized_out (64,512,256), indices (64,256,6) as f32,
//          mean_loss, mean_perplexity   -> d_out flat f32, 8486914 elems
//
// R10 -> R11: refine rework. R10 probe: t_refine ~= 37-41us x6 = 240us
// (51% of total); counters show latency-bound (VALU 9.5%, HBM 23%,
// occ 50% -- nothing busy; 77MB traffic = 14us floor). Old structure:
// wave-per-row with serial candidate loop (~2+k dependent 6-shfl
// reductions, MLP ~2 loads). New: block-per-row (grid 16384 x 256),
// 4 waves split the masked candidate set round-robin (serial chain /4),
// per-wave best packed (fkey(de)<<32)|cc -> LDS min (exact same argmin
// + tie-break), residual update coalesced across all 256 threads.
// gemm/prep/final byte-identical to R8; shadow instrumentation removed.
// ---------------------------------------------------------------------------

#define NTROWS 16384
#define DDIM   512
#define CCODES 1024
#define QSTAGE 6

// ws layout (bytes)
#define OFF_R      ((size_t)0)           // fp32 residual  NT*D*4   = 33554432
#define OFF_RBF    ((size_t)33554432)    // bf16 residual  NT*D*2   = 16777216
#define OFF_CBBF   ((size_t)50331648)    // bf16 codebooks 6*1024*512*2 = 6291456
#define OFF_CAND   ((size_t)56623104)    // u32 cand       NT*32*4   = 2097152
#define OFF_CBSQ   ((size_t)58720256)    // f32 |c|^2, 6*1024*4
#define OFF_HIST   ((size_t)58744832)    // u32 hist, 6*1024*4
#define OFF_LOSS   ((size_t)58769408)    // f32 loss bins, 6*256*4
#define WS_END     ((size_t)58775552)

#define OUT_IDX_OFF  ((size_t)8388608)
#define OUT_SCAL_OFF ((size_t)8486912)

typedef __attribute__((ext_vector_type(8))) short short8;
typedef __attribute__((ext_vector_type(8))) unsigned short ushort8v;
typedef __attribute__((ext_vector_type(4))) float f32x4;

__device__ __forceinline__ unsigned short f2bf(float f) {
    uint32_t u = __float_as_uint(f);
    uint32_t r = (u + 0x7fffu + ((u >> 16) & 1u)) >> 16;   // RNE
    return (unsigned short)r;
}
__device__ __forceinline__ uint32_t fkey(float f) {        // order-preserving f32->u32
    uint32_t u = __float_as_uint(f);
    return u ^ ((uint32_t)((int32_t)u >> 31) | 0x80000000u);
}
__device__ __forceinline__ float funkey(uint32_t k) {
    uint32_t u = (k & 0x80000000u) ? (k ^ 0x80000000u) : ~k;
    return __uint_as_float(u);
}
__device__ __forceinline__ uint32_t umin32(uint32_t a, uint32_t b) { return a < b ? a : b; }
__device__ __forceinline__ uint32_t umax32(uint32_t a, uint32_t b) { return a > b ? a : b; }
__device__ __forceinline__ unsigned long long umin64(unsigned long long a,
                                                     unsigned long long b) {
    return a < b ? a : b;
}
__device__ __forceinline__ float wave_sum(float v) {
    for (int m = 32; m; m >>= 1) v += __shfl_xor(v, m, 64);
    return v;
}
__device__ __forceinline__ uint32_t wave_min_u32(uint32_t v) {
    for (int m = 32; m; m >>= 1) v = umin32(v, (uint32_t)__shfl_xor((int)v, m, 64));
    return v;
}
__device__ __forceinline__ void async_load16(const void* g, void* l) {
    __builtin_amdgcn_global_load_lds(
        (__attribute__((address_space(1))) void*)(void*)g,
        (__attribute__((address_space(3))) void*)l, 16, 0, 0);
}

// --------------------------------------------------------------------------
// prep: blocks [0,1536): bf16 codebooks + |c|^2 (+ zero hist/loss in blk 0)
//       blocks [1536,9728): transpose x (N,D,T) -> r (NT,D) fp32+bf16
// grid 9728 x 256
// --------------------------------------------------------------------------
__global__ __launch_bounds__(256) void prep_kernel(
    const float* __restrict__ x, const float* __restrict__ cb,
    float* __restrict__ r, unsigned short* __restrict__ rbf,
    unsigned short* __restrict__ cbbf, float* __restrict__ cbsq,
    unsigned int* __restrict__ hist, float* __restrict__ loss_bins)
{
    __shared__ float tile[32][33];
    if (blockIdx.x < 1536) {
        const int wave = threadIdx.x >> 6, lane = threadIdx.x & 63;
        const int row = blockIdx.x * 4 + wave;            // 0..6143
        const float* p = cb + (size_t)row * DDIM;
        unsigned short* pb = cbbf + (size_t)row * DDIM;
        float s = 0.f;
#pragma unroll
        for (int t = 0; t < 8; ++t) {
            float v = p[lane + 64 * t];
            pb[lane + 64 * t] = f2bf(v);
            s += v * v;
        }
        s = wave_sum(s);
        if (lane == 0) cbsq[row] = s;
        if (blockIdx.x == 0) {
            for (int i = threadIdx.x; i < QSTAGE * CCODES; i += 256) hist[i] = 0u;
            for (int i = threadIdx.x; i < QSTAGE * 256; i += 256) loss_bins[i] = 0.f;
        }
    } else {
        const int bidx = blockIdx.x - 1536;               // 0..8191
        const int d0 = (bidx & 15) * 32;
        const int t0 = ((bidx >> 4) & 7) * 32;
        const int n  = bidx >> 7;
        const int tx = threadIdx.x & 31, ty = threadIdx.x >> 5;
        const float* xp = x + (size_t)n * (DDIM * 256);
#pragma unroll
        for (int s = 0; s < 4; ++s) {
            int dd = ty + s * 8;
            tile[dd][tx] = xp[(size_t)(d0 + dd) * 256 + t0 + tx];
        }
        __syncthreads();
#pragma unroll
        for (int s = 0; s < 4; ++s) {
            int tt = ty + s * 8;
            float v = tile[tx][tt];
            size_t off = (size_t)(n * 256 + t0 + tt) * DDIM + d0 + tx;
            r[off] = v;
            rbf[off] = f2bf(v);
        }
    }
}

// --------------------------------------------------------------------------
// GEMM: dist'[row][col] = cbsq[col] - 2 * dot(r_row, c_col), bf16 MFMA.
// 256x256 block tile, BK=32, 4-deep LDS ring, counted vmcnt, 2-phase
// 16-MFMA grain. grid (64, 4) x 512 : tm = blockIdx.x, tn = blockIdx.y
// --------------------------------------------------------------------------
#define GBK 32
__global__ __launch_bounds__(512, 2) void gemm_dist_kernel(
    const unsigned short* __restrict__ Abf,   // NT x 512 bf16
    const unsigned short* __restrict__ Bbf,   // 1024 x 512 bf16 (stage slice)
    const float* __restrict__ cbsq,           // 1024 (stage slice)
    uint32_t* __restrict__ cand)              // NT x 16 x {k1,k2}
{
    __shared__ __align__(16) unsigned short lA[4][256][GBK];   // 64 KiB
    __shared__ __align__(16) unsigned short lB[4][256][GBK];   // 64 KiB
    const int tid = threadIdx.x;
    const int wave = tid >> 6, lane = tid & 63;
    const int quad = lane >> 4, l15 = lane & 15;
    const int tm = blockIdx.x, tn = blockIdx.y;
    const int wm = wave >> 2, wn = wave & 3;

    f32x4 acc[8][4];
#pragma unroll
    for (int i = 0; i < 8; ++i)
#pragma unroll
        for (int j = 0; j < 4; ++j) acc[i][j] = (f32x4){0.f, 0.f, 0.f, 0.f};

    const int srow = wave * 32 + (lane >> 2);
    const int gch  = (lane & 3) ^ ((lane >> 3) & 3);
    const unsigned short* gA0 = Abf + ((size_t)tm * 256 + srow) * DDIM + gch * 8;
    const unsigned short* gA1 = gA0 + 16 * DDIM;
    const unsigned short* gB0 = Bbf + ((size_t)tn * 256 + srow) * DDIM + gch * 8;
    const unsigned short* gB1 = gB0 + 16 * DDIM;
    const int dro0 = wave * 32, dro1 = wave * 32 + 16;

    // prologue: stage K-tiles 0,1,2 (12 issues/wave in flight)
#pragma unroll
    for (int st = 0; st < 3; ++st) {
        const size_t ko = (size_t)st * GBK;
        async_load16(gA0 + ko, &lA[st][dro0][0] + lane * 8);
        async_load16(gA1 + ko, &lA[st][dro1][0] + lane * 8);
        async_load16(gB0 + ko, &lB[st][dro0][0] + lane * 8);
        async_load16(gB1 + ko, &lB[st][dro1][0] + lane * 8);
    }
    asm volatile("s_waitcnt vmcnt(8)" ::: "memory");   // tile 0 landed
    __builtin_amdgcn_s_barrier();

    const int cq = (quad ^ ((l15 >> 1) & 3)) * 8;   // swizzled chunk addr

#pragma unroll
    for (int kt = 0; kt < 16; ++kt) {
        const int buf = kt & 3;
        const int sb  = (kt + 3) & 3;              // ring slot for tile kt+3
        const size_t ko = (size_t)(kt + 3) * GBK;

        // ================= phase 0: quadrant mh=0 =================
        short8 afA[4], bfr[4];
#pragma unroll
        for (int i = 0; i < 4; ++i)
            afA[i] = *(const short8*)&lA[buf][wm * 128 + i * 16 + l15][cq];
#pragma unroll
        for (int j = 0; j < 4; ++j)
            bfr[j] = *(const short8*)&lB[buf][wn * 64 + j * 16 + l15][cq];
        if (kt <= 12) {   // stage A-half of tile kt+3 (slot last read at kt-1)
            async_load16(gA0 + ko, &lA[sb][dro0][0] + lane * 8);
            async_load16(gA1 + ko, &lA[sb][dro1][0] + lane * 8);
        }
        __builtin_amdgcn_s_barrier();
        asm volatile("s_waitcnt lgkmcnt(0)" ::: "memory");
        __builtin_amdgcn_sched_barrier(0);         // rule #18
        __builtin_amdgcn_s_setprio(1);
#pragma unroll
        for (int i = 0; i < 4; ++i)
#pragma unroll
            for (int j = 0; j < 4; ++j)
                acc[i][j] = __builtin_amdgcn_mfma_f32_16x16x32_bf16(
                    afA[i], bfr[j], acc[i][j], 0, 0, 0);
        __builtin_amdgcn_s_setprio(0);
        __builtin_amdgcn_s_barrier();

        // ================= phase 1: quadrant mh=1 =================
        short8 afB[4];
#pragma unroll
        for (int i = 0; i < 4; ++i)
            afB[i] = *(const short8*)&lA[buf][wm * 128 + (i + 4) * 16 + l15][cq];
        if (kt <= 12) {   // stage B-half of tile kt+3
            async_load16(gB0 + ko, &lB[sb][dro0][0] + lane * 8);
            async_load16(gB1 + ko, &lB[sb][dro1][0] + lane * 8);
        }
        __builtin_amdgcn_s_barrier();
        asm volatile("s_waitcnt lgkmcnt(0)" ::: "memory");
        __builtin_amdgcn_sched_barrier(0);         // rule #18
        __builtin_amdgcn_s_setprio(1);
#pragma unroll
        for (int i = 0; i < 4; ++i)
#pragma unroll
            for (int j = 0; j < 4; ++j)
                acc[i + 4][j] = __builtin_amdgcn_mfma_f32_16x16x32_bf16(
                    afB[i], bfr[j], acc[i + 4][j], 0, 0, 0);
        __builtin_amdgcn_s_setprio(0);

        // tile boundary: counted — tiles kt+2,kt+3 (8 issues) stay in flight.
        if (kt <= 12)      asm volatile("s_waitcnt vmcnt(8)" ::: "memory");
        else if (kt == 13) asm volatile("s_waitcnt vmcnt(4)" ::: "memory");
        else if (kt == 14) asm volatile("s_waitcnt vmcnt(0)" ::: "memory");
        if (kt < 15) __builtin_amdgcn_s_barrier();
    }

    // epilogue: C/D layout col=lane&15, row=quad*4+reg (m89-verified).
    const int rowq = tm * 256 + wm * 128 + quad * 4;
    const int colb = tn * 256 + wn * 64 + l15;
    const int g    = tn * 4 + wn;
    float cbs[4];
#pragma unroll
    for (int j = 0; j < 4; ++j) cbs[j] = cbsq[colb + j * 16];
#pragma unroll
    for (int i = 0; i < 8; ++i) {
#pragma unroll
        for (int reg = 0; reg < 4; ++reg) {
            const int row = rowq + i * 16 + reg;
            uint32_t k[4];
#pragma unroll
            for (int j = 0; j < 4; ++j) {
                float dv = cbs[j] - 2.0f * acc[i][j][reg];
                k[j] = (fkey(dv) & ~1023u) | (uint32_t)(colb + j * 16);
            }
            // top-2 of 4 (tournament)
            uint32_t m01 = umin32(k[0], k[1]), M01 = umax32(k[0], k[1]);
            uint32_t m23 = umin32(k[2], k[3]), M23 = umax32(k[2], k[3]);
            uint32_t k1 = umin32(m01, m23);
            uint32_t k2 = umin32(umax32(m01, m23), umin32(M01, M23));
            // merge across the 16 lanes of this quad (xor stays in-quad)
#pragma unroll
            for (int m = 1; m < 16; m <<= 1) {
                uint32_t o1 = (uint32_t)__shfl_xor((int)k1, m, 64);
                uint32_t o2 = (uint32_t)__shfl_xor((int)k2, m, 64);
                uint32_t n1 = umin32(k1, o1);
                uint32_t n2 = umin32(umax32(k1, o1), umin32(k2, o2));
                k1 = n1; k2 = n2;
            }
            if (l15 == 0)
                *(uint2*)&cand[((size_t)row * 16 + g) * 2] = make_uint2(k1, k2);
        }
    }
}

// --------------------------------------------------------------------------
// refine+update (block-per-row): grid 16384 x 256.
// 4 waves/row: each wave loads the full row (2KB, L1-hot) + computes its
// own sumx; identical wave-uniform candidate mask; wave w handles masked
// candidates at positions == w (mod 4); per-wave best packed
// (fkey(de)<<32)|cc -> LDS min of 4 (exact argmin + tie-break preserved);
// residual update coalesced across all 256 threads (float2/thread).
// --------------------------------------------------------------------------
#define MARGIN 8.0f
__global__ __launch_bounds__(256) void refine_kernel(
    float* __restrict__ r, unsigned short* __restrict__ rbf,
    const float* __restrict__ cbq, const float* __restrict__ cbsqq,
    const uint32_t* __restrict__ cand,
    float* __restrict__ out_idx, unsigned int* __restrict__ histq,
    float* __restrict__ loss_bins, int q, int write_bf)
{
    __shared__ unsigned long long sbest[4];
    const int tid = threadIdx.x;
    const int wave = tid >> 6, lane = tid & 63;
    const int nt = blockIdx.x;

    // candidate keys (identical per wave; lanes >=32 idle-high)
    uint32_t key = 0xFFFFFFFFu;
    if (lane < 32) key = cand[(size_t)nt * 32 + lane];

    // full row in regs (each wave redundantly; L1-hot after first wave)
    const float4* r4 = (const float4*)(r + (size_t)nt * DDIM);
    float4 ra = r4[lane * 2], rb = r4[lane * 2 + 1];
    float s = ra.x * ra.x + ra.y * ra.y + ra.z * ra.z + ra.w * ra.w
            + rb.x * rb.x + rb.y * rb.y + rb.z * rb.z + rb.w * rb.w;
    const float sumx = wave_sum(s);

    const uint32_t kmin = wave_min_u32(key);
    const float thr = funkey(kmin & ~1023u) + MARGIN;
    unsigned long long mask = __ballot(lane < 32 && funkey(key & ~1023u) <= thr);

    float best = 1e30f;
    int bestc = CCODES;
    int cnt = 0;
    while (mask) {
        const int src = __ffsll(mask) - 1;
        mask &= mask - 1;
        if ((cnt++ & 3) != wave) continue;   // round-robin split across 4 waves
        const int cc = __shfl((int)(key & 1023u), src, 64);
        const float4* crow = (const float4*)(cbq + (size_t)cc * DDIM);
        float4 ca = crow[lane * 2], cb2 = crow[lane * 2 + 1];
        float dot = ra.x * ca.x + ra.y * ca.y + ra.z * ca.z + ra.w * ca.w
                  + rb.x * cb2.x + rb.y * cb2.y + rb.z * cb2.z + rb.w * cb2.w;
        dot = wave_sum(dot);
        const float de = (sumx - 2.0f * dot) + cbsqq[cc];
        if (de < best || (de == best && cc < bestc)) { best = de; bestc = cc; }
    }
    if (lane == 0)
        sbest[wave] = ((unsigned long long)fkey(best) << 32) | (unsigned)bestc;
    __syncthreads();
    const unsigned long long bmin =
        umin64(umin64(sbest[0], sbest[1]), umin64(sbest[2], sbest[3]));
    bestc = (int)(bmin & 0xFFFFFFFFu);
    best  = funkey((uint32_t)(bmin >> 32));

    // coalesced residual update: 256 threads x float2 = 512 floats
    const float2* rr  = (const float2*)(r + (size_t)nt * DDIM);
    const float2* cbr = (const float2*)(cbq + (size_t)bestc * DDIM);
    float2 rv = rr[tid], cv = cbr[tid];
    float2 nv = make_float2(rv.x - cv.x, rv.y - cv.y);
    ((float2*)(r + (size_t)nt * DDIM))[tid] = nv;
    if (write_bf) {
        uint32_t pk = (uint32_t)f2bf(nv.x) | ((uint32_t)f2bf(nv.y) << 16);
        ((uint32_t*)(rbf + (size_t)nt * DDIM))[tid] = pk;
    }

    if (tid == 0) {
        out_idx[(size_t)nt * QSTAGE + q] = (float)bestc;
        atomicAdd(&histq[bestc], 1u);
        atomicAdd(&loss_bins[q * 256 + (blockIdx.x & 255)], best);
    }
}

// --------------------------------------------------------------------------
// final: blocks [0,8192): out = x - r_final transposed back to (N,D,T);
//        block 8192: mean commit loss + mean perplexity
// grid 8193 x 256
// --------------------------------------------------------------------------
__global__ __launch_bounds__(256) void final_kernel(
    const float* __restrict__ x, const float* __restrict__ r,
    float* __restrict__ out,
    const unsigned int* __restrict__ hist, const float* __restrict__ loss_bins,
    float* __restrict__ out2)
{
    __shared__ float tile[32][33];    // [t'][d']
    __shared__ float red[4];
    __shared__ float perp_acc;
    const int tid = threadIdx.x, wave = tid >> 6, lane = tid & 63;

    if (blockIdx.x < 8192) {
        const int bidx = blockIdx.x;
        const int d0 = (bidx & 15) * 32;
        const int t0 = ((bidx >> 4) & 7) * 32;
        const int n  = bidx >> 7;
        const int tx = tid & 31, ty = tid >> 5;
#pragma unroll
        for (int s = 0; s < 4; ++s) {
            int tt = ty + s * 8;
            tile[tt][tx] = r[(size_t)(n * 256 + t0 + tt) * DDIM + d0 + tx];
        }
        __syncthreads();
        const float* xp = x + (size_t)n * (DDIM * 256);
        float* op = out + (size_t)n * (DDIM * 256);
#pragma unroll
        for (int s = 0; s < 4; ++s) {
            int dd = ty + s * 8;
            size_t off = (size_t)(d0 + dd) * 256 + t0 + tx;
            op[off] = xp[off] - tile[tx][dd];
        }
        return;
    }

    // scalars block
    if (tid == 0) perp_acc = 0.f;
    __syncthreads();
    for (int q = 0; q < QSTAGE; ++q) {
        float s = 0.f;
        for (int c = tid; c < CCODES; c += 256) {
            float p = (float)hist[q * CCODES + c] * (1.0f / (float)NTROWS);
            s += p * logf(p + 1e-10f);
        }
        s = wave_sum(s);
        if (lane == 0) red[wave] = s;
        __syncthreads();
        if (tid == 0) {
            float tot = red[0] + red[1] + red[2] + red[3];
            perp_acc += expf(-tot);
        }
        __syncthreads();
    }
    float ls = 0.f;
    for (int i = tid; i < QSTAGE * 256; i += 256) ls += loss_bins[i];
    ls = wave_sum(ls);
    if (lane == 0) red[wave] = ls;
    __syncthreads();
    if (tid == 0) {
        float lsum = red[0] + red[1] + red[2] + red[3];
        out2[0] = (lsum / (float)QSTAGE) / ((float)NTROWS * (float)DDIM);
        out2[1] = perp_acc / (float)QSTAGE;
    }
}

// --------------------------------------------------------------------------
extern "C" void kernel_launch(void* const* d_in, const int* in_sizes, int n_in,
                              void* d_out, int out_size, void* d_ws, size_t ws_size,
                              hipStream_t stream)
{
    const float* x  = (const float*)d_in[0];
    const float* cb = (const float*)d_in[1];
    float* out = (float*)d_out;
    char* ws = (char*)d_ws;

    float*          r      = (float*)(ws + OFF_R);
    unsigned short* rbf    = (unsigned short*)(ws + OFF_RBF);
    unsigned short* cbbf   = (unsigned short*)(ws + OFF_CBBF);
    uint32_t*       cand   = (uint32_t*)(ws + OFF_CAND);
    float*          cbsq   = (float*)(ws + OFF_CBSQ);
    unsigned int*   hist   = (unsigned int*)(ws + OFF_HIST);
    float*          lbins  = (float*)(ws + OFF_LOSS);

    prep_kernel<<<9728, 256, 0, stream>>>(x, cb, r, rbf, cbbf, cbsq, hist, lbins);

    for (int q = 0; q < QSTAGE; ++q) {
        const size_t cboff = (size_t)q * CCODES * DDIM;
        gemm_dist_kernel<<<dim3(64, 4), 512, 0, stream>>>(
            rbf, cbbf + cboff, cbsq + q * CCODES, cand);
        refine_kernel<<<NTROWS, 256, 0, stream>>>(
            r, rbf, cb + cboff, cbsq + q * CCODES, cand,
            out + OUT_IDX_OFF, hist + q * CCODES, lbins,
            q, (q < QSTAGE - 1) ? 1 : 0);
    }

    final_kernel<<<8193, 256, 0, stream>>>(x, r, out, hist, lbins,
                                           out + OUT_SCAL_OFF);
}